// Round 1
// baseline (701.029 us; speedup 1.0000x reference)
//
#include <hip/hip_runtime.h>

#define HDIM 128
#define H3   384
#define RDIM 20
#define NPB  8   // nodes per block (node MLP)
#define EPB  8   // edges per block (edge kernel)

// -------- Kernel 1: per-node MLP  P = silu(s@W1+b1) @ W2 + b2  --------
__global__ __launch_bounds__(128) void node_mlp_kernel(
    const float* __restrict__ s, const float* __restrict__ W1,
    const float* __restrict__ b1, const float* __restrict__ W2,
    const float* __restrict__ b2, float* __restrict__ P, int N)
{
    __shared__ float sS[NPB][HDIM];
    __shared__ float sH[NPB][HDIM];
    const int t  = threadIdx.x;
    const int n0 = blockIdx.x * NPB;

    #pragma unroll
    for (int n = 0; n < NPB; ++n) {
        int node = n0 + n;
        sS[n][t] = (node < N) ? s[(size_t)node * HDIM + t] : 0.f;
    }
    __syncthreads();

    // stage 1: h[t] = silu(sum_k s[k]*W1[k][t] + b1[t])
    float acc[NPB];
    #pragma unroll
    for (int n = 0; n < NPB; ++n) acc[n] = 0.f;
    for (int k = 0; k < HDIM; ++k) {
        float w = W1[k * HDIM + t];
        #pragma unroll
        for (int n = 0; n < NPB; ++n) acc[n] += sS[n][k] * w;
    }
    float bb = b1[t];
    #pragma unroll
    for (int n = 0; n < NPB; ++n) {
        float z = acc[n] + bb;
        sH[n][t] = z / (1.f + __expf(-z));   // silu
    }
    __syncthreads();

    // stage 2: P[t3] = sum_k h[k]*W2[k][t3] + b2[t3], t3 in {t, t+128, t+256}
    float a0[NPB], a1[NPB], a2[NPB];
    #pragma unroll
    for (int n = 0; n < NPB; ++n) { a0[n] = 0.f; a1[n] = 0.f; a2[n] = 0.f; }
    for (int k = 0; k < HDIM; ++k) {
        float w0 = W2[k * H3 + t];
        float w1 = W2[k * H3 + t + 128];
        float w2 = W2[k * H3 + t + 256];
        #pragma unroll
        for (int n = 0; n < NPB; ++n) {
            float hv = sH[n][k];
            a0[n] += hv * w0;
            a1[n] += hv * w1;
            a2[n] += hv * w2;
        }
    }
    float c0 = b2[t], c1 = b2[t + 128], c2 = b2[t + 256];
    #pragma unroll
    for (int n = 0; n < NPB; ++n) {
        int node = n0 + n;
        if (node < N) {
            size_t base = (size_t)node * H3;
            P[base + t]       = a0[n] + c0;
            P[base + t + 128] = a1[n] + c1;
            P[base + t + 256] = a2[n] + c2;
        }
    }
}

// -------- Kernel 2: per-edge filter + gather + scatter-add --------
__global__ __launch_bounds__(128) void edge_kernel(
    const float* __restrict__ rbf, const float* __restrict__ cutoff,
    const float* __restrict__ evec, const float* __restrict__ Wr,
    const float* __restrict__ br, const float* __restrict__ P,
    const float* __restrict__ v, const int* __restrict__ eidx,
    float* __restrict__ ds, float* __restrict__ dv, int E)
{
    const int t  = threadIdx.x;
    const int e0 = blockIdx.x * EPB;

    __shared__ float sRbf[EPB][RDIM];
    __shared__ float sVec[EPB][3];
    __shared__ float sCut[EPB];
    __shared__ int   sI[EPB], sJ[EPB];

    for (int x = t; x < EPB * RDIM; x += 128) {
        int n = x / RDIM, k = x % RDIM;
        int e = e0 + n;
        sRbf[n][k] = (e < E) ? rbf[(size_t)e * RDIM + k] : 0.f;
    }
    if (t < EPB * 3) {
        int n = t / 3, d = t % 3;
        int e = e0 + n;
        sVec[n][d] = (e < E) ? evec[(size_t)e * 3 + d] : 0.f;
    }
    if (t < EPB) {
        int e = e0 + t;
        sCut[t] = (e < E) ? cutoff[e] : 0.f;
        sI[t]   = (e < E) ? eidx[e] : 0;
        sJ[t]   = (e < E) ? eidx[E + e] : 0;
    }
    __syncthreads();

    // W_e = rbf @ Wr  (bias+cutoff applied later); thread t owns cols t, t+128, t+256
    float w0[EPB], w1[EPB], w2[EPB];
    #pragma unroll
    for (int n = 0; n < EPB; ++n) { w0[n] = 0.f; w1[n] = 0.f; w2[n] = 0.f; }
    #pragma unroll
    for (int k = 0; k < RDIM; ++k) {
        float c0 = Wr[k * H3 + t];
        float c1 = Wr[k * H3 + t + 128];
        float c2 = Wr[k * H3 + t + 256];
        #pragma unroll
        for (int n = 0; n < EPB; ++n) {
            float r = sRbf[n][k];
            w0[n] += r * c0;
            w1[n] += r * c1;
            w2[n] += r * c2;
        }
    }
    float br0 = br[t], br1 = br[t + 128], br2 = br[t + 256];

    #pragma unroll
    for (int n = 0; n < EPB; ++n) {
        int e = e0 + n;
        if (e >= E) break;
        int i = sI[n], j = sJ[n];
        float cu = sCut[n];
        size_t pj = (size_t)j * H3;
        float xss = (w0[n] + br0) * cu * P[pj + t];
        float xsv = (w1[n] + br1) * cu * P[pj + t + 128];
        float xvv = (w2[n] + br2) * cu * P[pj + t + 256];

        float vx = v[pj + t];         // v[j][0][t], row stride 3*H = 384
        float vy = v[pj + 128 + t];
        float vz = v[pj + 256 + t];
        float ex = sVec[n][0], ey = sVec[n][1], ez = sVec[n][2];
        float inner = vx * ex + vy * ey + vz * ez;
        float coef  = xsv + inner * xvv;

        size_t di = (size_t)i * HDIM;
        size_t dvi = (size_t)i * H3;
        atomicAdd(&ds[di + t],        xss);
        atomicAdd(&dv[dvi + t],       coef * ex);
        atomicAdd(&dv[dvi + 128 + t], coef * ey);
        atomicAdd(&dv[dvi + 256 + t], coef * ez);
    }
}

extern "C" void kernel_launch(void* const* d_in, const int* in_sizes, int n_in,
                              void* d_out, int out_size, void* d_ws, size_t ws_size,
                              hipStream_t stream)
{
    const float* s    = (const float*)d_in[0];
    const float* v    = (const float*)d_in[1];
    const float* rbf  = (const float*)d_in[2];
    const float* cut  = (const float*)d_in[3];
    const float* evec = (const float*)d_in[4];
    const float* W1   = (const float*)d_in[5];
    const float* b1   = (const float*)d_in[6];
    const float* W2   = (const float*)d_in[7];
    const float* b2   = (const float*)d_in[8];
    const float* Wr   = (const float*)d_in[9];
    const float* br   = (const float*)d_in[10];
    const int*   eidx = (const int*)d_in[11];

    const int N = in_sizes[0] / HDIM;   // 20000
    const int E = in_sizes[3];          // 400000

    float* out = (float*)d_out;
    float* ds  = out;                           // [N, H]
    float* dv  = out + (size_t)N * HDIM;        // [N, 3, H]
    float* P   = (float*)d_ws;                  // [N, 3H] scratch

    hipMemsetAsync(d_out, 0, (size_t)out_size * sizeof(float), stream);

    node_mlp_kernel<<<(N + NPB - 1) / NPB, 128, 0, stream>>>(s, W1, b1, W2, b2, P, N);
    edge_kernel<<<(E + EPB - 1) / EPB, 128, 0, stream>>>(rbf, cut, evec, Wr, br, P, v,
                                                         eidx, ds, dv, E);
}

// Round 2
// 319.494 us; speedup vs baseline: 2.1942x; 2.1942x over previous
//
#include <hip/hip_runtime.h>

#define HDIM 128
#define H3   384
#define RDIM 20
#define NPB  8    // nodes per block (node MLP)
#define CHNK 64   // edge chunk per block in reduce kernel

// -------- Kernel 1: per-node MLP  P = silu(s@W1+b1) @ W2 + b2  --------
__global__ __launch_bounds__(128) void node_mlp_kernel(
    const float* __restrict__ s, const float* __restrict__ W1,
    const float* __restrict__ b1, const float* __restrict__ W2,
    const float* __restrict__ b2, float* __restrict__ P, int N)
{
    __shared__ float sS[NPB][HDIM];
    __shared__ float sH[NPB][HDIM];
    const int t  = threadIdx.x;
    const int n0 = blockIdx.x * NPB;

    #pragma unroll
    for (int n = 0; n < NPB; ++n) {
        int node = n0 + n;
        sS[n][t] = (node < N) ? s[(size_t)node * HDIM + t] : 0.f;
    }
    __syncthreads();

    float acc[NPB];
    #pragma unroll
    for (int n = 0; n < NPB; ++n) acc[n] = 0.f;
    for (int k = 0; k < HDIM; ++k) {
        float w = W1[k * HDIM + t];
        #pragma unroll
        for (int n = 0; n < NPB; ++n) acc[n] += sS[n][k] * w;
    }
    float bb = b1[t];
    #pragma unroll
    for (int n = 0; n < NPB; ++n) {
        float z = acc[n] + bb;
        sH[n][t] = z / (1.f + __expf(-z));   // silu
    }
    __syncthreads();

    float a0[NPB], a1[NPB], a2[NPB];
    #pragma unroll
    for (int n = 0; n < NPB; ++n) { a0[n] = 0.f; a1[n] = 0.f; a2[n] = 0.f; }
    for (int k = 0; k < HDIM; ++k) {
        float w0 = W2[k * H3 + t];
        float w1 = W2[k * H3 + t + 128];
        float w2 = W2[k * H3 + t + 256];
        #pragma unroll
        for (int n = 0; n < NPB; ++n) {
            float hv = sH[n][k];
            a0[n] += hv * w0;
            a1[n] += hv * w1;
            a2[n] += hv * w2;
        }
    }
    float c0 = b2[t], c1 = b2[t + 128], c2 = b2[t + 256];
    #pragma unroll
    for (int n = 0; n < NPB; ++n) {
        int node = n0 + n;
        if (node < N) {
            size_t base = (size_t)node * H3;
            P[base + t]       = a0[n] + c0;
            P[base + t + 128] = a1[n] + c1;
            P[base + t + 256] = a2[n] + c2;
        }
    }
}

// -------- CSR build --------
__global__ void hist_kernel(const int* __restrict__ eidx, int* __restrict__ counts, int E)
{
    int e = blockIdx.x * 256 + threadIdx.x;
    if (e < E) atomicAdd(&counts[eidx[e]], 1);
}

__global__ __launch_bounds__(1024) void scan_kernel(
    const int* __restrict__ counts, int* __restrict__ rstart,
    int* __restrict__ cursor, int N)
{
    __shared__ int part[1024];
    const int t = threadIdx.x;
    const int C = 20;               // 1024*20 >= 20000
    int loc[C];
    int s = 0;
    #pragma unroll
    for (int q = 0; q < C; ++q) {
        int idx = t * C + q;
        int c = (idx < N) ? counts[idx] : 0;
        loc[q] = s; s += c;
    }
    part[t] = s;
    __syncthreads();
    for (int off = 1; off < 1024; off <<= 1) {
        int vv = (t >= off) ? part[t - off] : 0;
        __syncthreads();
        part[t] += vv;
        __syncthreads();
    }
    int boff = (t > 0) ? part[t - 1] : 0;
    #pragma unroll
    for (int q = 0; q < C; ++q) {
        int idx = t * C + q;
        if (idx < N) {
            int st = boff + loc[q];
            rstart[idx] = st;
            cursor[idx] = st;
        }
    }
    if (t == 1023) rstart[N] = part[1023];
}

__global__ void scatter_kernel(const int* __restrict__ eidx, int* __restrict__ cursor,
                               int* __restrict__ eord, int E)
{
    int e = blockIdx.x * 256 + threadIdx.x;
    if (e < E) {
        int i = eidx[e];
        int pos = atomicAdd(&cursor[i], 1);
        eord[pos] = e;
    }
}

// -------- Kernel 2: node-centric gather-reduce --------
__global__ __launch_bounds__(128) void reduce_kernel(
    const int* __restrict__ rstart, const int* __restrict__ eord,
    const float* __restrict__ rbf, const float* __restrict__ cutoff,
    const float* __restrict__ evec, const float* __restrict__ Wr,
    const float* __restrict__ br, const float* __restrict__ P,
    const float* __restrict__ v, const int* __restrict__ eidx,
    float* __restrict__ ds, float* __restrict__ dv, int E)
{
    const int t = threadIdx.x;
    const int i = blockIdx.x;

    // Wr columns for this thread, held in registers for the whole row
    float wr0[RDIM], wr1[RDIM], wr2[RDIM];
    #pragma unroll
    for (int k = 0; k < RDIM; ++k) {
        wr0[k] = Wr[k * H3 + t];
        wr1[k] = Wr[k * H3 + t + 128];
        wr2[k] = Wr[k * H3 + t + 256];
    }
    float br0 = br[t], br1 = br[t + 128], br2 = br[t + 256];

    int beg = rstart[i], end = rstart[i + 1];
    float accs = 0.f, accx = 0.f, accy = 0.f, accz = 0.f;

    __shared__ int sE[CHNK], sJ[CHNK];

    for (int c0 = beg; c0 < end; c0 += CHNK) {
        int cnt = min(CHNK, end - c0);
        __syncthreads();
        if (t < cnt) {
            int e = eord[c0 + t];
            sE[t] = e;
            sJ[t] = eidx[E + e];
        }
        __syncthreads();
        for (int q = 0; q < cnt; ++q) {
            int e = sE[q], j = sJ[q];
            float cu = cutoff[e];
            float ex = evec[3 * e], ey = evec[3 * e + 1], ez = evec[3 * e + 2];
            const float4* rb4 = (const float4*)(rbf + (size_t)e * RDIM);
            float w0 = 0.f, w1 = 0.f, w2 = 0.f;
            #pragma unroll
            for (int k4 = 0; k4 < 5; ++k4) {
                float4 r = rb4[k4];
                w0 += r.x * wr0[4*k4+0] + r.y * wr0[4*k4+1] + r.z * wr0[4*k4+2] + r.w * wr0[4*k4+3];
                w1 += r.x * wr1[4*k4+0] + r.y * wr1[4*k4+1] + r.z * wr1[4*k4+2] + r.w * wr1[4*k4+3];
                w2 += r.x * wr2[4*k4+0] + r.y * wr2[4*k4+1] + r.z * wr2[4*k4+2] + r.w * wr2[4*k4+3];
            }
            size_t pj = (size_t)j * H3;
            float xss = (w0 + br0) * cu * P[pj + t];
            float xsv = (w1 + br1) * cu * P[pj + 128 + t];
            float xvv = (w2 + br2) * cu * P[pj + 256 + t];
            float inner = v[pj + t] * ex + v[pj + 128 + t] * ey + v[pj + 256 + t] * ez;
            float coef = xsv + inner * xvv;
            accs += xss;
            accx += coef * ex;
            accy += coef * ey;
            accz += coef * ez;
        }
    }

    size_t di  = (size_t)i * HDIM;
    size_t dvi = (size_t)i * H3;
    ds[di + t]        = accs;
    dv[dvi + t]       = accx;
    dv[dvi + 128 + t] = accy;
    dv[dvi + 256 + t] = accz;
}

extern "C" void kernel_launch(void* const* d_in, const int* in_sizes, int n_in,
                              void* d_out, int out_size, void* d_ws, size_t ws_size,
                              hipStream_t stream)
{
    const float* s    = (const float*)d_in[0];
    const float* v    = (const float*)d_in[1];
    const float* rbf  = (const float*)d_in[2];
    const float* cut  = (const float*)d_in[3];
    const float* evec = (const float*)d_in[4];
    const float* W1   = (const float*)d_in[5];
    const float* b1   = (const float*)d_in[6];
    const float* W2   = (const float*)d_in[7];
    const float* b2   = (const float*)d_in[8];
    const float* Wr   = (const float*)d_in[9];
    const float* br   = (const float*)d_in[10];
    const int*   eidx = (const int*)d_in[11];

    const int N = in_sizes[0] / HDIM;   // 20000
    const int E = in_sizes[3];          // 400000

    float* out = (float*)d_out;
    float* ds  = out;                      // [N, H]
    float* dv  = out + (size_t)N * HDIM;   // [N, 3, H]

    // workspace layout (all 256B aligned)
    char* w = (char*)d_ws;
    float* P      = (float*)w;                       w += (size_t)N * H3 * sizeof(float);
    int*   counts = (int*)w;                         w += ((size_t)N * 4 + 255) / 256 * 256;
    int*   rstart = (int*)w;                         w += ((size_t)(N + 1) * 4 + 255) / 256 * 256;
    int*   cursor = (int*)w;                         w += ((size_t)N * 4 + 255) / 256 * 256;
    int*   eord   = (int*)w;

    hipMemsetAsync(counts, 0, (size_t)N * sizeof(int), stream);

    node_mlp_kernel<<<(N + NPB - 1) / NPB, 128, 0, stream>>>(s, W1, b1, W2, b2, P, N);
    hist_kernel<<<(E + 255) / 256, 256, 0, stream>>>(eidx, counts, E);
    scan_kernel<<<1, 1024, 0, stream>>>(counts, rstart, cursor, N);
    scatter_kernel<<<(E + 255) / 256, 256, 0, stream>>>(eidx, cursor, eord, E);
    reduce_kernel<<<N, 128, 0, stream>>>(rstart, eord, rbf, cut, evec, Wr, br, P, v,
                                         eidx, ds, dv, E);
}